// Round 4
// baseline (81.441 us; speedup 1.0000x reference)
//
#include <hip/hip_runtime.h>

#define NH 300          // hidden units
#define BLK 256
#define RPT 4           // rows per thread

// ws layout:
//   [0, NH*16)        : float4 coef[j] = {a_j, b_j, c_j, 0.5*W32_j}
//   [NH*16, NH*16+12) : float W31prime[3]  (bias-folded linear term)

__global__ __launch_bounds__(320)
void phi2_precompute(const float* __restrict__ varphi1,   // [300,3]
                     const float* __restrict__ varphi2,   // [300]
                     const float* __restrict__ l1,        // [3]
                     const float* __restrict__ l2,        // [300]
                     const float* __restrict__ l3,        // [1]
                     float4* __restrict__ coef,
                     float* __restrict__ w31p) {
    __shared__ float red[5][3];
    int j = threadIdx.x;
    float p0 = 0.f, p1 = 0.f, p2 = 0.f;
    if (j < NH) {
        float lv2  = l2[j];
        float phi2 = varphi2[j];
        // W_32[j] = phi2*l2_j - l3*phi2
        float W32 = phi2 * (lv2 - l3[0]);
        float v0 = varphi1[j*3+0], v1 = varphi1[j*3+1], v2 = varphi1[j*3+2];
        // W_21[j,k] = varphi1[j,k]*(l1[k] - l2[j])
        float a = v0 * (l1[0] - lv2);
        float b = v1 * (l1[1] - lv2);
        float c = v2 * (l1[2] - lv2);
        coef[j] = make_float4(a, b, c, 0.5f * W32);
        // W31'_k = sum_j W32_j * (0.5*W21[j,k] - varphi1[j,k])
        p0 = W32 * (0.5f * a - v0);
        p1 = W32 * (0.5f * b - v1);
        p2 = W32 * (0.5f * c - v2);
    }
    // 64-lane wave reduction
    for (int off = 32; off > 0; off >>= 1) {
        p0 += __shfl_down(p0, off);
        p1 += __shfl_down(p1, off);
        p2 += __shfl_down(p2, off);
    }
    int wave = threadIdx.x >> 6;
    if ((threadIdx.x & 63) == 0) {
        red[wave][0] = p0; red[wave][1] = p1; red[wave][2] = p2;
    }
    __syncthreads();
    if (threadIdx.x == 0) {
        float s0 = 0.f, s1 = 0.f, s2 = 0.f;
        for (int w = 0; w < 5; ++w) { s0 += red[w][0]; s1 += red[w][1]; s2 += red[w][2]; }
        w31p[0] = s0; w31p[1] = s1; w31p[2] = s2;
    }
}

__global__ __launch_bounds__(BLK)
void phi2_main(const float* __restrict__ x,       // [B,2]
               const float4* __restrict__ coef,   // [300]
               const float* __restrict__ w31p,    // [3]
               float* __restrict__ y,             // [B]
               int B) {
    __shared__ float4 scoef[NH];
    for (int i = threadIdx.x; i < NH; i += BLK) scoef[i] = coef[i];
    float w0 = w31p[0], w1 = w31p[1], w2 = w31p[2];
    __syncthreads();

    int base = blockIdx.x * (BLK * RPT) + threadIdx.x;
    float x0[RPT], x1[RPT], acc[RPT];
#pragma unroll
    for (int r = 0; r < RPT; ++r) {
        int row = base + r * BLK;
        float2 xv = (row < B) ? ((const float2*)x)[row] : make_float2(0.f, 0.f);
        x0[r] = xv.x; x1[r] = xv.y;
        acc[r] = fmaf(w0, xv.x, fmaf(w1, xv.y, w2));  // folded linear part
    }

#pragma unroll 4
    for (int j = 0; j < NH; ++j) {
        float4 cf = scoef[j];   // wave-uniform ds_read_b128 -> broadcast
#pragma unroll
        for (int r = 0; r < RPT; ++r) {
            float d = fmaf(cf.x, x0[r], fmaf(cf.y, x1[r], cf.z));
            acc[r] = fmaf(cf.w, fabsf(d), acc[r]);   // |d| is a free VOP3 modifier
        }
    }

#pragma unroll
    for (int r = 0; r < RPT; ++r) {
        int row = base + r * BLK;
        if (row < B) y[row] = acc[r];
    }
}

extern "C" void kernel_launch(void* const* d_in, const int* in_sizes, int n_in,
                              void* d_out, int out_size, void* d_ws, size_t ws_size,
                              hipStream_t stream) {
    const float* x       = (const float*)d_in[0];
    const float* varphi1 = (const float*)d_in[1];
    const float* varphi2 = (const float*)d_in[2];
    const float* l1      = (const float*)d_in[3];
    const float* l2      = (const float*)d_in[4];
    const float* l3      = (const float*)d_in[5];

    float4* coef = (float4*)d_ws;
    float*  w31p = (float*)((char*)d_ws + NH * sizeof(float4));
    float*  y    = (float*)d_out;

    int B = in_sizes[0] / 2;

    phi2_precompute<<<1, 320, 0, stream>>>(varphi1, varphi2, l1, l2, l3, coef, w31p);

    int grid = (B + BLK * RPT - 1) / (BLK * RPT);
    phi2_main<<<grid, BLK, 0, stream>>>(x, coef, w31p, y, B);
}